// Round 3
// baseline (2458.607 us; speedup 1.0000x reference)
//
#include <hip/hip_runtime.h>

typedef unsigned short u16;
typedef unsigned int   u32;

#define N_NODES    15000
#define N_EDGES    30000
#define NUM_GRAPHS 600
#define N_STEMS    6000
#define N_JBONDS   3000

// d_out flat layout: [0,1200) final, [1200,631200) stem_preds, [631200,634200) jbond
#define OUT_FINAL  0
#define OUT_STEM   1200
#define OUT_JB     631200

// K-extent of folded a1/M tensors: 64 real + 1 bias column + 7 zero pad = 72
#define KP 72
#define N_CVT 26

__device__ __forceinline__ float u2f(u16 v){ union{u32 i; float f;} c; c.i=((u32)v)<<16; return c.f; }
__device__ __forceinline__ u16  f2b(float f){ union{float f; u32 u;} c; c.f=f; u32 u=c.u;
                                              return (u16)((u + 0x7fffu + ((u>>16)&1u))>>16); }
__device__ __forceinline__ float lrelu(float x){ return x>0.f ? x : 0.01f*x; }
__device__ __forceinline__ float sigmoidf(float x){ return 1.f/(1.f+expf(-x)); }

__device__ __forceinline__ float dot64_f(const float* __restrict__ w, const float4* __restrict__ x4){
  const float4* wp = (const float4*)w;
  float acc = 0.f;
  #pragma unroll
  for(int c=0;c<16;c++){ float4 a=wp[c], b=x4[c]; acc += a.x*b.x+a.y*b.y+a.z*b.z+a.w*b.w; }
  return acc;
}

__device__ __forceinline__ int lower_bound_i(const int* __restrict__ a, int n, int v){
  int lo=0, hi=n;
  while(lo<hi){ int m=(lo+hi)>>1; if(a[m]<v) lo=m+1; else hi=m; }
  return lo;
}

__device__ __forceinline__ void store_out(void* dout, int isf, int idx, float v){
  if(isf) ((float*)dout)[idx] = v;
  else    ((u16*)dout)[idx]   = f2b(v);
}

// ---------------- dtype sniff: any bf16-NaN/Inf bit pattern in x => inputs are f32 ----------------
__global__ __launch_bounds__(256) void k_sniff(const u16* __restrict__ x, int n, int* __restrict__ flag){
  int i = blockIdx.x*256 + threadIdx.x;
  int local = 0;
  for(; i < n; i += gridDim.x*256){
    u16 v = x[i];
    if(((v>>7)&0xFFu) == 0xFFu) local = 1;
  }
  if(local) atomicOr(flag, 1);
}

// ---------------- convert all float inputs to f32 (from bf16 or passthrough) ----------------
struct CvtArgs { const void* src[N_CVT]; float* dst[N_CVT]; int n[N_CVT]; };

__global__ __launch_bounds__(256) void k_cvt(CvtArgs A, const int* __restrict__ flag){
  int isf = *flag;
  int tid = blockIdx.x*256 + threadIdx.x;
  int stride = gridDim.x*256;
  for(int b=0; b<N_CVT; b++){
    int n = A.n[b];
    const float* sf = (const float*)A.src[b];
    const u16*   sb = (const u16*)A.src[b];
    float* d = A.dst[b];
    for(int i=tid; i<n; i+=stride) d[i] = isf ? sf[i] : u2f(sb[i]);
  }
}

// ---------------- lin0 ----------------
__global__ __launch_bounds__(64) void k_lin0(const float* __restrict__ x, const float* __restrict__ w,
                                             const float* __restrict__ b,
                                             float* __restrict__ outF, float* __restrict__ hF){
  int n = blockIdx.x, o = threadIdx.x;
  __shared__ float xs[14];
  if(o<14) xs[o] = x[n*14+o];
  __syncthreads();
  float acc = b[o];
  #pragma unroll
  for(int i=0;i<14;i++) acc += xs[i]*w[o*14+i];
  acc = lrelu(acc);
  outF[n*64+o] = acc;
  hF[n*64+o]   = acc;
}

// ---------------- a1~[e][KP]: lrelu(en1(edge_attr)); k=64 -> 1, k>64 -> 0 ----------------
__global__ __launch_bounds__(128) void k_a1(const float* __restrict__ ea,
                                            const float* __restrict__ en1w, const float* __restrict__ en1b,
                                            float* __restrict__ a1){
  int e = blockIdx.x, k = threadIdx.x;
  if(k >= KP) return;
  float v;
  if(k < 64){
    float acc = en1b[k];
    #pragma unroll
    for(int c=0;c<4;c++) acc += ea[e*4+c] * en1w[k*4+c];
    v = lrelu(acc);
  } else v = (k==64) ? 1.0f : 0.0f;
  a1[(size_t)e*KP + k] = v;
}

// ---------------- W2f[j][k][o]: k<64 -> en2_w[(j*64+o)*64+k]; k==64 -> en2_b[j*64+o]; else 0 ----
__global__ __launch_bounds__(256) void k_packW2(const float* __restrict__ en2w, const float* __restrict__ en2b,
                                                float* __restrict__ W2f){
  int idx = blockIdx.x*256 + threadIdx.x;
  if(idx >= 64*KP*64) return;
  int o = idx & 63;
  int r2 = idx >> 6;
  int k = r2 % KP;
  int j = r2 / KP;
  float v = 0.f;
  if(k < 64)       v = en2w[((size_t)(j*64+o))*64 + k];
  else if(k == 64) v = en2b[j*64+o];
  W2f[idx] = v;
}

// ---------------- rootT[o][j] = root_w[j][o] ----------------
__global__ __launch_bounds__(256) void k_rootT(const float* __restrict__ root, float* __restrict__ rootT){
  int i = blockIdx.x*256 + threadIdx.x;
  if(i < 4096){ int r=i>>6, c=i&63; rootT[c*64+r] = root[i]; }
}

// ---------------- per-edge counts: deg over dst, cnt over src ----------------
__global__ __launch_bounds__(256) void k_degcnt(const int* __restrict__ ei,
                                                float* __restrict__ deg, int* __restrict__ cnt){
  int e = blockIdx.x*256 + threadIdx.x;
  if(e < N_EDGES){
    atomicAdd(&deg[ei[N_EDGES + e]], 1.0f);
    atomicAdd(&cnt[ei[e]], 1);
  }
}

// ---------------- exclusive scan of cnt -> offs[15001], pos=offs ----------------
__global__ __launch_bounds__(1024) void k_scan(const int* __restrict__ cnt,
                                               int* __restrict__ offs, int* __restrict__ pos){
  __shared__ int s[1024];
  int t = threadIdx.x;
  int base = t*15;
  int c[15];
  int loc = 0;
  #pragma unroll
  for(int i=0;i<15;i++){ int idx=base+i; int v=(idx<N_NODES)?cnt[idx]:0; c[i]=v; loc+=v; }
  s[t]=loc; __syncthreads();
  for(int d=1; d<1024; d<<=1){
    int v2 = (t>=d)? s[t-d] : 0;
    __syncthreads();
    s[t] += v2;
    __syncthreads();
  }
  int run = s[t]-loc;
  #pragma unroll
  for(int i=0;i<15;i++){
    int idx=base+i;
    if(idx<N_NODES){ offs[idx]=run; pos[idx]=run; }
    run += c[i];
  }
  if(t==1023) offs[N_NODES]=s[1023];
}

// ---------------- CSR fill: eidx grouped by src ----------------
__global__ __launch_bounds__(256) void k_fill(const int* __restrict__ ei,
                                              int* __restrict__ pos, int* __restrict__ eidx){
  int e = blockIdx.x*256 + threadIdx.x;
  if(e < N_EDGES){
    int slot = atomicAdd(&pos[ei[e]], 1);
    eidx[slot] = e;
  }
}

// ---------------- fused M-build + message scatter ----------------
__global__ __launch_bounds__(512) void k_fused(const float* __restrict__ outF, const float* __restrict__ a1,
                                               const float* __restrict__ W2f,
                                               const int* __restrict__ ei_dst,
                                               const int* __restrict__ offs, const int* __restrict__ eidx,
                                               float* __restrict__ agg){
  int kc = threadIdx.x >> 6, o = threadIdx.x & 63;
  int nb = blockIdx.x * 8;
  __shared__ float outs[8][64];
  __shared__ float red[8][64];
  outs[kc][o] = outF[(nb+kc)*64 + o];
  __syncthreads();

  float Macc[8][9];
  #pragma unroll
  for(int n=0;n<8;n++)
    #pragma unroll
    for(int i=0;i<9;i++) Macc[n][i] = 0.f;

  for(int j=0;j<64;j++){
    const float* wr = W2f + ((size_t)j*KP + kc*9)*64 + o;
    float wv[9];
    #pragma unroll
    for(int i=0;i<9;i++) wv[i] = wr[i*64];
    #pragma unroll
    for(int n=0;n<8;n++){
      float oj = outs[n][j];
      #pragma unroll
      for(int i=0;i<9;i++) Macc[n][i] += oj * wv[i];
    }
  }

  #pragma unroll
  for(int n=0;n<8;n++){
    int node = nb + n;
    int lo = offs[node], hi = offs[node+1];    // block-uniform -> barrier-safe
    for(int t=lo; t<hi; t++){
      int e = eidx[t];
      int dst = ei_dst[e];
      const float* ap = a1 + (size_t)e*KP + kc*9;
      float p = 0.f;
      #pragma unroll
      for(int i=0;i<9;i++) p += ap[i] * Macc[n][i];
      red[kc][o] = p;
      __syncthreads();
      if(kc == 0){
        float s2 = red[0][o]+red[1][o]+red[2][o]+red[3][o]
                 + red[4][o]+red[5][o]+red[6][o]+red[7][o];
        atomicAdd(&agg[dst*64 + o], s2);
      }
      __syncthreads();
    }
  }
}

// ---------------- node update: m = lrelu(agg/deg + out@root_w + conv_b); GRU ----------------
__global__ __launch_bounds__(64) void k_node(const float* __restrict__ agg, const float* __restrict__ deg,
                                             float* __restrict__ outF, float* __restrict__ hF,
                                             const float* __restrict__ rootT, const float* __restrict__ convb,
                                             const float* __restrict__ wih, const float* __restrict__ whh,
                                             const float* __restrict__ bih, const float* __restrict__ bhh){
  int n = blockIdx.x, o = threadIdx.x;
  __shared__ __align__(16) float outs[64], ms[64], hs[64];
  outs[o] = outF[n*64+o];
  hs[o]   = hF[n*64+o];
  __syncthreads();
  float acc = agg[n*64+o] / fmaxf(deg[n], 1.0f) + convb[o];
  {
    const float4* rp = (const float4*)(rootT + o*64);
    const float4* op = (const float4*)outs;
    #pragma unroll
    for(int c=0;c<16;c++){ float4 w=rp[c], v=op[c]; acc += v.x*w.x+v.y*w.y+v.z*w.z+v.w*w.w; }
  }
  ms[o] = lrelu(acc);
  __syncthreads();
  float ir = bih[o], iz = bih[64+o], in_ = bih[128+o];
  float hr = bhh[o], hz = bhh[64+o], hn  = bhh[128+o];
  {
    const float4* mp = (const float4*)ms;
    const float4* hp = (const float4*)hs;
    const float4* w0 = (const float4*)(wih + o*64);
    const float4* w1 = (const float4*)(wih + (64+o)*64);
    const float4* w2 = (const float4*)(wih + (128+o)*64);
    const float4* u0 = (const float4*)(whh + o*64);
    const float4* u1 = (const float4*)(whh + (64+o)*64);
    const float4* u2 = (const float4*)(whh + (128+o)*64);
    #pragma unroll
    for(int c=0;c<16;c++){
      float4 m4 = mp[c], h4 = hp[c];
      float4 a;
      a = w0[c]; ir  += m4.x*a.x+m4.y*a.y+m4.z*a.z+m4.w*a.w;
      a = w1[c]; iz  += m4.x*a.x+m4.y*a.y+m4.z*a.z+m4.w*a.w;
      a = w2[c]; in_ += m4.x*a.x+m4.y*a.y+m4.z*a.z+m4.w*a.w;
      a = u0[c]; hr  += h4.x*a.x+h4.y*a.y+h4.z*a.z+h4.w*a.w;
      a = u1[c]; hz  += h4.x*a.x+h4.y*a.y+h4.z*a.z+h4.w*a.w;
      a = u2[c]; hn  += h4.x*a.x+h4.y*a.y+h4.z*a.z+h4.w*a.w;
    }
  }
  float r  = sigmoidf(ir+hr);
  float z  = sigmoidf(iz+hz);
  float ng = tanhf(in_ + r*hn);
  float hnew = (1.f - z)*ng + z*hs[o];
  hF[n*64+o]   = hnew;
  outF[n*64+o] = hnew;
}

// ---------------- stem head ----------------
__global__ __launch_bounds__(128) void k_stem(const float* __restrict__ outF, const int* __restrict__ sidx,
                                              const float* __restrict__ s1w, const float* __restrict__ s1b,
                                              const float* __restrict__ s2w, const float* __restrict__ s2b,
                                              void* __restrict__ dout, const int* __restrict__ flag){
  int s = blockIdx.x, t = threadIdx.x;
  int isf = *flag;
  __shared__ __align__(16) float xs[64], hid[64];
  int a = sidx[s];
  if(t<64) xs[t] = outF[a*64+t];
  __syncthreads();
  if(t<64) hid[t] = lrelu(s1b[t] + dot64_f(s1w + t*64, (const float4*)xs));
  __syncthreads();
  if(t<105){
    float acc = s2b[t] + dot64_f(s2w + t*64, (const float4*)hid);
    store_out(dout, isf, OUT_STEM + s*105 + t, acc);
  }
}

// ---------------- jbond head ----------------
__global__ __launch_bounds__(128) void k_jbond(const float* __restrict__ outF, const int* __restrict__ jidx,
                                               const float* __restrict__ j1w, const float* __restrict__ j1b,
                                               const float* __restrict__ j2w, const float* __restrict__ j2b,
                                               void* __restrict__ dout, const int* __restrict__ flag){
  int jb = blockIdx.x, t = threadIdx.x;
  int isf = *flag;
  __shared__ __align__(16) float xs[2][64], hid[2][64];
  int at = t>>6, k = t&63;
  int a = jidx[jb*2 + at];
  xs[at][k] = outF[a*64+k];
  __syncthreads();
  hid[at][k] = lrelu(j1b[k] + dot64_f(j1w + k*64, (const float4*)xs[at]));
  __syncthreads();
  if(t<64){
    float p = (hid[0][t] + hid[1][t]) * j2w[t];
    #pragma unroll
    for(int s=32;s;s>>=1) p += __shfl_xor(p, s, 64);
    if(t==0) store_out(dout, isf, OUT_JB + jb, 0.5f*p + j2b[0]);
  }
}

// ---------------- Set2Set (1 step, zero init) + final linear ----------------
__global__ __launch_bounds__(64) void k_s2s(const float* __restrict__ outF, const int* __restrict__ batch,
                                            const float* __restrict__ bih, const float* __restrict__ bhh,
                                            const float* __restrict__ loutw, const float* __restrict__ loutb,
                                            void* __restrict__ dout, const int* __restrict__ flag){
  int b = blockIdx.x, t = threadIdx.x;
  int isf = *flag;
  float i_ = bih[t]     + bhh[t];
  float g_ = bih[128+t] + bhh[128+t];
  float o_ = bih[192+t] + bhh[192+t];
  float c  = sigmoidf(i_)*tanhf(g_);
  float q  = sigmoidf(o_)*tanhf(c);

  int lo = lower_bound_i(batch, N_NODES, b);
  int hi = lower_bound_i(batch, N_NODES, b+1);

  float emax = -3.4e38f;
  for(int n=lo;n<hi;n++){
    float p = outF[n*64+t]*q;
    #pragma unroll
    for(int s=32;s;s>>=1) p += __shfl_xor(p, s, 64);
    emax = fmaxf(emax, p);
  }
  float Z = 0.f, racc = 0.f;
  for(int n=lo;n<hi;n++){
    float v = outF[n*64+t];
    float p = v*q;
    #pragma unroll
    for(int s=32;s;s>>=1) p += __shfl_xor(p, s, 64);
    float w = expf(p - emax);
    Z += w; racc += w*v;
  }
  float rp = (hi>lo) ? racc/Z : 0.f;

  #pragma unroll
  for(int j=0;j<2;j++){
    float p = q*loutw[j*128+t] + rp*loutw[j*128+64+t];
    #pragma unroll
    for(int s=32;s;s>>=1) p += __shfl_xor(p, s, 64);
    if(t==0) store_out(dout, isf, OUT_FINAL + b*2 + j, p + loutb[j]);
  }
}

extern "C" void kernel_launch(void* const* d_in, const int* in_sizes, int n_in,
                              void* d_out, int out_size, void* d_ws, size_t ws_size,
                              hipStream_t stream) {
  const int* edge_index  = (const int*)d_in[28];
  const int* stem_atmidx = (const int*)d_in[29];
  const int* jbond_atmidx= (const int*)d_in[30];
  const int* batch       = (const int*)d_in[31];

  char* ws = (char*)d_ws;
  size_t off = 0;
  auto alloc = [&](size_t bytes)->void*{ void* p = ws + off; off = (off + bytes + 255) & ~(size_t)255; return p; };

  int*   flag = (int*)  alloc(4);
  float* outF = (float*)alloc((size_t)N_NODES*64*4);
  float* hF   = (float*)alloc((size_t)N_NODES*64*4);
  float* agg  = (float*)alloc((size_t)N_NODES*64*4);
  float* a1   = (float*)alloc((size_t)N_EDGES*KP*4);
  float* W2f  = (float*)alloc((size_t)64*KP*64*4);
  float* deg  = (float*)alloc((size_t)N_NODES*4);
  int*   cnt  = (int*)  alloc((size_t)N_NODES*4);
  int*   offs = (int*)  alloc((size_t)(N_NODES+1)*4);
  int*   pos  = (int*)  alloc((size_t)N_NODES*4);
  int*   eidx = (int*)  alloc((size_t)N_EDGES*4);
  float* rootT= (float*)alloc(4096*4);

  // converted f32 copies of the float inputs (indices 0..21, 24..27)
  static const int cvt_idx[N_CVT] = {0,1,2,3,4,5,6,7,8,9,10,11,12,13,14,15,16,17,18,19,20,21,24,25,26,27};
  CvtArgs A;
  float* cF[N_CVT];
  for(int i=0;i<N_CVT;i++){
    int src = cvt_idx[i];
    int n = in_sizes[src];
    cF[i] = (float*)alloc((size_t)n*4);
    A.src[i] = d_in[src];
    A.dst[i] = cF[i];
    A.n[i]   = n;
  }
  (void)ws_size; (void)n_in; (void)out_size;
  // named views of converted buffers
  float* xF=cF[0];   float* eaF=cF[1];  float* l0w=cF[2];  float* l0b=cF[3];
  float* e1w=cF[4];  float* e1b=cF[5];  float* e2w=cF[6];  float* e2b=cF[7];
  float* rootw=cF[8];float* convb=cF[9];
  float* wih=cF[10]; float* whh=cF[11]; float* bih=cF[12]; float* bhh=cF[13];
  float* s1w=cF[14]; float* s1b=cF[15]; float* s2w=cF[16]; float* s2b=cF[17];
  float* j1w=cF[18]; float* j1b=cF[19]; float* j2w=cF[20]; float* j2b=cF[21];
  float* lbih=cF[22];float* lbhh=cF[23];float* loutw=cF[24];float* loutb=cF[25];

  hipMemsetAsync(flag, 0, 4, stream);
  hipMemsetAsync(deg,  0, (size_t)N_NODES*4, stream);
  hipMemsetAsync(cnt,  0, (size_t)N_NODES*4, stream);

  k_sniff <<<128, 256, 0, stream>>>((const u16*)d_in[0], in_sizes[0], flag);
  k_cvt   <<<512, 256, 0, stream>>>(A, flag);

  k_lin0  <<<N_NODES, 64, 0, stream>>>(xF, l0w, l0b, outF, hF);
  k_a1    <<<N_EDGES, 128, 0, stream>>>(eaF, e1w, e1b, a1);
  k_packW2<<<(64*KP*64+255)/256, 256, 0, stream>>>(e2w, e2b, W2f);
  k_rootT <<<16, 256, 0, stream>>>(rootw, rootT);
  k_degcnt<<<(N_EDGES+255)/256, 256, 0, stream>>>(edge_index, deg, cnt);
  k_scan  <<<1, 1024, 0, stream>>>(cnt, offs, pos);
  k_fill  <<<(N_EDGES+255)/256, 256, 0, stream>>>(edge_index, pos, eidx);

  for(int it=0; it<6; it++){
    hipMemsetAsync(agg, 0, (size_t)N_NODES*64*4, stream);
    k_fused<<<N_NODES/8, 512, 0, stream>>>(outF, a1, W2f, edge_index + N_EDGES, offs, eidx, agg);
    k_node <<<N_NODES, 64, 0, stream>>>(agg, deg, outF, hF, rootT, convb, wih, whh, bih, bhh);
  }

  k_stem <<<N_STEMS, 128, 0, stream>>>(outF, stem_atmidx, s1w, s1b, s2w, s2b, d_out, flag);
  k_jbond<<<N_JBONDS, 128, 0, stream>>>(outF, jbond_atmidx, j1w, j1b, j2w, j2b, d_out, flag);
  k_s2s  <<<NUM_GRAPHS, 64, 0, stream>>>(outF, batch, lbih, lbhh, loutw, loutb, d_out, flag);
}